// Round 12
// baseline (2457.219 us; speedup 1.0000x reference)
//
#include <hip/hip_runtime.h>

#define NB 4
#define NPER 8192
#define MPER 2048
#define KNN 16
#define CIN 64
#define CO 128
#define MTOT (NB*MPER)
#define CPB 56          // knn chunks per batch: 24x64q + 8x32q + 8x16q + 16x8q

typedef unsigned long long u64;
typedef unsigned int u32;

__device__ __forceinline__ float med3f(float a, float b, float c) {
    return __builtin_amdgcn_fmed3f(a, b, c);
}

// ---------------- init: zero stats + progress, write row_splits ----------------
__global__ void k_init(float* __restrict__ stats, float* __restrict__ rs,
                       u32* __restrict__ prog) {
    int t = threadIdx.x;
    if (t < 256) stats[t] = 0.f;
    if (t < 128) prog[t] = 0u;
    if (t < 5) rs[t] = (float)(t * MPER);
}

// DPP compare-select step on a packed u64 key (max).
#define DPPSTEP(key, CTRL, RM) do {                                                   \
    unsigned lo_ = (unsigned)(key), hi_ = (unsigned)((key) >> 32);                    \
    unsigned nlo = (unsigned)__builtin_amdgcn_update_dpp((int)lo_, (int)lo_, CTRL, RM, 0xf, false); \
    unsigned nhi = (unsigned)__builtin_amdgcn_update_dpp((int)hi_, (int)hi_, CTRL, RM, 0xf, false); \
    unsigned long long ok_ = ((unsigned long long)nhi << 32) | nlo;                   \
    if (ok_ > (key)) (key) = ok_;                                                     \
} while (0)

#define DPP6(key) do { \
    DPPSTEP(key, 0xB1,  0xF); \
    DPPSTEP(key, 0x4E,  0xF); \
    DPPSTEP(key, 0x141, 0xF); \
    DPPSTEP(key, 0x140, 0xF); \
    DPPSTEP(key, 0x142, 0xA); \
    DPPSTEP(key, 0x143, 0xC); \
} while (0)

// ---------------- megakernel: blocks 0-3 = FPS, blocks 4-227 = KNN+stats ----------------
struct __align__(16) FpsSM {
    float4 spt[256 * 33];      // padded point table: lane t slot s -> t*33+s (bank-safe b128)
    u32    klo[2][4];          // parity-double-buffered wave partials (SoA)
    u32    khi[2][4];
    float  rx[2][4];
    float  ry[2][4];
    float  rz[2][4];
};
struct KnnSM {
    float4 sp[2][2112];        // staged chunk, per-sub stride P+2 (bank-safe)
    float  ndl[256][16];
    u32    candl[256][16];     // d < tau candidates (globally <= 15)
    u32    eql[256][16];       // d == tau candidates
    int    ccnt[256], ecnt[256];
    u32    pcur[256];
    float  taub[64];
    u32    nidxL[64][16];      // merged neighbor ids (global point ids)
    float4 g4[2][16][18];      // gather staging for stats (double-buffered)
};
#define SMBYTES (sizeof(FpsSM) > sizeof(KnnSM) ? sizeof(FpsSM) : sizeof(KnnSM))

__launch_bounds__(256, 1)
__global__ void k_mega(const float* __restrict__ pts, const float* __restrict__ feat,
                       const float* __restrict__ W, float* __restrict__ out_np,
                       float4* __restrict__ qpts, u32* __restrict__ prog,
                       float* __restrict__ ymax, float* __restrict__ ymin,
                       float* __restrict__ stats) {
    #pragma clang fp contract(off)
    __shared__ __align__(16) char SMRAW[SMBYTES];
    const int t = threadIdx.x;

    if (blockIdx.x < NB) {
        // ========== FPS (R2-proven math; carried-xyz reduction, R10 store pattern) ==========
        FpsSM& sm = *(FpsSM*)SMRAW;
        const int b = blockIdx.x;
        const float4* pb4 = (const float4*)(pts + (size_t)b * NPER * 3);

        float f[96];
        #pragma unroll
        for (int j = 0; j < 24; ++j) {
            float4 v = pb4[t * 24 + j];
            f[j*4+0] = v.x; f[j*4+1] = v.y; f[j*4+2] = v.z; f[j*4+3] = v.w;
        }
        float px[32], py[32], pz[32], dd[32];
        #pragma unroll
        for (int s = 0; s < 32; ++s) {
            px[s] = f[3*s]; py[s] = f[3*s+1]; pz[s] = f[3*s+2];
            dd[s] = 1e10f;
            sm.spt[t * 33 + s] = make_float4(px[s], py[s], pz[s], 0.f);
        }
        if (t == 0) {
            size_t row = (size_t)b * MPER;
            out_np[row*3+0] = px[0]; out_np[row*3+1] = py[0]; out_np[row*3+2] = pz[0];
            qpts[row] = make_float4(px[0], py[0], pz[0], 0.f);
        }
        __syncthreads();

        float4 c0 = sm.spt[0];                 // lane0 slot0 -> index 0
        float cx = c0.x, cy = c0.y, cz = c0.z;
        const int wv = t >> 6;
        const int ibase = t * 32;

        for (int i = 1; i < MPER; ++i) {
            float bv = -1.f; int bs = 0;
            #pragma unroll
            for (int s = 0; s < 32; ++s) {
                float dx = px[s] - cx, dy = py[s] - cy, dz = pz[s] - cz;
                float t0 = dx * dx, t1 = dy * dy, t2 = dz * dz;
                float d = (t0 + t1) + t2;
                float nd = fminf(dd[s], d);
                dd[s] = nd;
                bool bet = nd > bv;
                bv = bet ? nd : bv;
                bs = bet ? s : bs;
            }
            u64 myk = ((u64)__float_as_uint(bv) << 32) | (u32)~(u32)(ibase + bs);
            // own-best xyz fetch: issued now, latency hides under the DPP reduce
            float4 bxyz = sm.spt[t * 33 + bs];

            u64 key = myk;
            DPP6(key);                          // lane 63 holds the wave max

            // broadcast max; the (unique) winner lane writes key+xyz partials
            u32 tlo = (u32)__builtin_amdgcn_readlane((int)(u32)key, 63);
            u32 thi = (u32)__builtin_amdgcn_readlane((int)(u32)(key >> 32), 63);
            u64 kmax = ((u64)thi << 32) | tlo;
            const int p = i & 1;
            if (myk == kmax) {
                sm.klo[p][wv] = (u32)myk;  sm.khi[p][wv] = (u32)(myk >> 32);
                sm.rx[p][wv] = bxyz.x; sm.ry[p][wv] = bxyz.y; sm.rz[p][wv] = bxyz.z;
            }
            __syncthreads();            // single barrier; parity buffer avoids WAW

            // publisher on wave 1 (R10-proven): prior stores drained by the barrier
            if (t == 64 && (((i & 127) == 0) || (i >= 1536 && (i & 31) == 0))) {
                __hip_atomic_store(prog + b * 32, (u32)i,
                                   __ATOMIC_RELEASE, __HIP_MEMORY_SCOPE_AGENT);
            }

            // cross-wave pick: keys + xyz muxed, no second LDS hop
            uint4  KL = *(const uint4*)sm.klo[p];
            uint4  KH = *(const uint4*)sm.khi[p];
            float4 RX = *(const float4*)sm.rx[p];
            float4 RY = *(const float4*)sm.ry[p];
            float4 RZ = *(const float4*)sm.rz[p];
            u64 k0 = ((u64)KH.x << 32) | KL.x;
            u64 k1 = ((u64)KH.y << 32) | KL.y;
            u64 k2 = ((u64)KH.z << 32) | KL.z;
            u64 k3 = ((u64)KH.w << 32) | KL.w;
            bool cA = k0 > k1;
            u64 kA = cA ? k0 : k1;
            float xA = cA ? RX.x : RX.y, yA = cA ? RY.x : RY.y, zA = cA ? RZ.x : RZ.y;
            bool cB = k2 > k3;
            u64 kB = cB ? k2 : k3;
            float xB = cB ? RX.z : RX.w, yB = cB ? RY.z : RY.w, zB = cB ? RZ.z : RZ.w;
            bool cF = kA > kB;
            cx = cF ? xA : xB; cy = cF ? yA : yB; cz = cF ? zA : zB;

            if (t == 0) {
                size_t row = (size_t)b * MPER + i;
                out_np[row*3+0] = cx; out_np[row*3+1] = cy; out_np[row*3+2] = cz;
                qpts[row] = make_float4(cx, cy, cz, 0.f);
            }
        }
        __syncthreads();   // drains the final row's stores (vmcnt(0) per wave)
        if (t == 64) {
            __hip_atomic_store(prog + b * 32, (u32)MPER,
                               __ATOMIC_RELEASE, __HIP_MEMORY_SCOPE_AGENT);
        }
    } else {
        // ============ KNN (R9-proven math) + folded stats, gated on progress ============
        KnnSM& sm = *(KnnSM*)SMRAW;
        const int kb = blockIdx.x - NB;
        const int b  = kb / CPB;
        const int r  = kb % CPB;
        int nq, q0b;
        if (r < 24)      { nq = 64; q0b = r << 6; }
        else if (r < 32) { nq = 32; q0b = 1536 + ((r - 24) << 5); }
        else if (r < 40) { nq = 16; q0b = 1792 + ((r - 32) << 4); }
        else             { nq = 8;  q0b = 1920 + ((r - 40) << 3); }
        const int lgL = (nq == 64) ? 2 : (nq == 32) ? 3 : (nq == 16) ? 4 : 5;
        const int L = 1 << lgL;          // lanes per query
        const int lgP = 11 - lgL;
        const int P = 1 << lgP;          // points per lane per 2048-chunk
        const int stride = P + 2;        // float4 units; bank-offset 8 between subs
        const u32 need = (u32)(q0b + nq);

        // single-thread spin (de-stormed gate), then block-wide fence
        if (t == 0) {
            while (__hip_atomic_load(prog + b * 32, __ATOMIC_RELAXED,
                                     __HIP_MEMORY_SCOPE_AGENT) < need)
                __builtin_amdgcn_s_sleep(32);
        }
        __syncthreads();
        __threadfence();

        const int sub = t & (L - 1), qloc = t >> lgL;
        const int q = b * MPER + q0b + qloc;
        const float4 qp = qpts[q];
        const float qq = (qp.x * qp.x + qp.y * qp.y) + qp.z * qp.z;
        const float* pb = pts + (size_t)b * NPER * 3;
        const int wq = t >> 6, wl = t & 63;

        float4 Lr[6];
        #define LOADC(c) do { const float4* src_ = (const float4*)(pb + (size_t)(c) * 2048 * 3); \
            _Pragma("unroll") for (int u_ = 0; u_ < 6; ++u_) Lr[u_] = src_[t * 6 + u_]; } while (0)
        #define WRITEC(pbuf) do { \
            float fl_[24]; \
            _Pragma("unroll") for (int u_ = 0; u_ < 6; ++u_) { \
                fl_[u_*4+0]=Lr[u_].x; fl_[u_*4+1]=Lr[u_].y; fl_[u_*4+2]=Lr[u_].z; fl_[u_*4+3]=Lr[u_].w; } \
            _Pragma("unroll") for (int r_ = 0; r_ < 8; ++r_) { \
                float x_=fl_[3*r_], y_=fl_[3*r_+1], z_=fl_[3*r_+2]; \
                float pp_=(x_*x_ + y_*y_) + z_*z_; \
                int gpos_ = wq*512 + wl*8 + r_; \
                sm.sp[pbuf][(gpos_ >> lgP)*stride + (gpos_ & (P-1))] = make_float4(x_,y_,z_,pp_); } } while (0)

        // ---- pass 1: per-lane sorted top-16 distances over my P-pt sub-streams ----
        float nd[16];
        #pragma unroll
        for (int j = 0; j < 16; ++j) nd[j] = 1e30f;

        LOADC(0); WRITEC(0); LOADC(1);
        __syncthreads();
        for (int c = 0; c < 4; ++c) {
            const int pbuf = c & 1;
            const float4* rowp = &sm.sp[pbuf][sub * stride];
            #pragma unroll 4
            for (int j = 0; j < P; ++j) {
                float4 p = rowp[j];
                float dot = (qp.x * p.x + qp.y * p.y) + qp.z * p.z;
                float d = (qq + p.w) - 2.f * dot;
                if (d < nd[15]) {
                    #pragma unroll
                    for (int u = 15; u >= 1; --u) nd[u] = med3f(d, nd[u-1], nd[u]);
                    nd[0] = fminf(nd[0], d);
                }
            }
            __syncthreads();
            if (c < 3) {
                WRITEC((c + 1) & 1);
                if (c < 2) LOADC(c + 2);
                __syncthreads();
            }
        }
        #pragma unroll
        for (int j = 0; j < 16; ++j) sm.ndl[t][j] = nd[j];
        __syncthreads();

        // leader: exact 16th-smallest via med3-insertion over L sorted lists (early break)
        if (sub == 0) {
            float td[16];
            #pragma unroll
            for (int u = 0; u < 16; ++u) td[u] = 1e30f;
            for (int s = 0; s < L; ++s) {
                for (int u2 = 0; u2 < 16; ++u2) {
                    float v = sm.ndl[t + s][u2];
                    if (!(v < td[15])) break;     // row ascending -> rest can't insert
                    #pragma unroll
                    for (int u = 15; u >= 1; --u) td[u] = med3f(v, td[u-1], td[u]);
                    td[0] = fminf(td[0], v);
                }
            }
            sm.taub[qloc] = td[15];
        }
        __syncthreads();
        const float tau = sm.taub[qloc];

        // ---- pass 2: collect (d<tau) and (d==tau) separately (bit-identical recompute) ----
        int cnt = 0, ecn = 0;
        LOADC(0); WRITEC(0); LOADC(1);
        __syncthreads();
        for (int c = 0; c < 4; ++c) {
            const int pbuf = c & 1;
            const float4* rowp = &sm.sp[pbuf][sub * stride];
            for (int j = 0; j < P; ++j) {
                float4 p = rowp[j];
                float dot = (qp.x * p.x + qp.y * p.y) + qp.z * p.z;
                float d = (qq + p.w) - 2.f * dot;
                if (d <= tau) {
                    u32 pidx = (u32)(c * 2048 + (sub << lgP) + j);
                    if (d < tau) { if (cnt < 16) sm.candl[t][cnt++] = pidx; }
                    else         { if (ecn < 16) sm.eql[t][ecn++] = pidx; }
                }
            }
            __syncthreads();
            if (c < 3) {
                WRITEC((c + 1) & 1);
                if (c < 2) LOADC(c + 2);
                __syncthreads();
            }
        }
        sm.ccnt[t] = cnt; sm.ecnt[t] = ecn; sm.pcur[t] = 0;
        __syncthreads();

        // leader: all <tau cands (order-free downstream), then ascending-index quota
        // fill from ==tau cands. Identical SET to reference top_k. Stash in LDS.
        if (sub == 0) {
            const int base = t;
            int kept = 0;
            for (int s = 0; s < L; ++s) {
                int n = sm.ccnt[base + s];
                for (int e = 0; e < n && kept < 16; ++e)
                    sm.nidxL[qloc][kept++] = (u32)(b * NPER) + sm.candl[base + s][e];
            }
            while (kept < 16) {
                u32 best = 0xFFFFFFFFu; int bs = -1;
                for (int s = 0; s < L; ++s) {
                    u32 ps = sm.pcur[base + s];
                    u32 v = (ps < (u32)sm.ecnt[base + s]) ? sm.eql[base + s][ps] : 0xFFFFFFFFu;
                    if (v < best) { best = v; bs = s; }
                }
                if (bs < 0) break;
                sm.pcur[base + bs]++;
                sm.nidxL[qloc][kept++] = (u32)(b * NPER) + best;
            }
        }
        __syncthreads();

        // ---- folded stats phase: thread = (channel o = t>>1, k-half kh = t&1) ----
        const int o = t >> 1, kh = t & 1;
        float w[68];
        {
            const float* wr = W + o * 67;
            #pragma unroll
            for (int c = 0; c < 64; ++c) w[c] = wr[3 + c];
            w[64] = wr[0]; w[65] = wr[1]; w[66] = wr[2]; w[67] = 0.f;
        }
        const int gn = t >> 4, gf = t & 15;   // gather: neighbor, float4-slot
        float ssum = 0.f, ssq = 0.f;

        float4 gfv, gxv = make_float4(0.f, 0.f, 0.f, 0.f);
        {
            int nid = (int)sm.nidxL[0][gn];
            gfv = ((const float4*)(feat + (size_t)nid * CIN))[gf];
            if (t < 16) {
                int nid2 = (int)sm.nidxL[0][t];
                float4 qp2 = qpts[(size_t)b * MPER + q0b];
                gxv = make_float4(pts[(size_t)nid2*3]   - qp2.x,
                                  pts[(size_t)nid2*3+1] - qp2.y,
                                  pts[(size_t)nid2*3+2] - qp2.z, 0.f);
            }
        }
        for (int mi = 0; mi < nq; ++mi) {
            const int buf = mi & 1;
            sm.g4[buf][gn][gf] = gfv;
            if (t < 16) sm.g4[buf][t][16] = gxv;
            if (mi + 1 < nq) {
                int nid = (int)sm.nidxL[mi+1][gn];
                gfv = ((const float4*)(feat + (size_t)nid * CIN))[gf];
                if (t < 16) {
                    int nid2 = (int)sm.nidxL[mi+1][t];
                    float4 qp2 = qpts[(size_t)b * MPER + q0b + mi + 1];
                    gxv = make_float4(pts[(size_t)nid2*3]   - qp2.x,
                                      pts[(size_t)nid2*3+1] - qp2.y,
                                      pts[(size_t)nid2*3+2] - qp2.z, 0.f);
                }
            }
            __syncthreads();
            float vmax = -1e30f, vmin = 1e30f;
            #pragma unroll 1
            for (int kk = 0; kk < 8; ++kk) {
                const int k = kh * 8 + kk;
                float y0 = 0.f, y1 = 0.f, y2 = 0.f, y3 = 0.f;
                #pragma unroll
                for (int c4 = 0; c4 < 17; ++c4) {
                    float4 gv = sm.g4[buf][k][c4];
                    y0 = fmaf(gv.x, w[c4*4+0], y0);
                    y1 = fmaf(gv.y, w[c4*4+1], y1);
                    y2 = fmaf(gv.z, w[c4*4+2], y2);
                    y3 = fmaf(gv.w, w[c4*4+3], y3);
                }
                float y = (y0 + y1) + (y2 + y3);
                vmax = fmaxf(vmax, y); vmin = fminf(vmin, y);
                ssum += y; ssq = fmaf(y, y, ssq);
            }
            float vM = fmaxf(vmax, __shfl_xor(vmax, 1));
            float vm = fminf(vmin, __shfl_xor(vmin, 1));
            if (kh == 0) {
                size_t mrow = (size_t)(b * MPER + q0b + mi) * CO + o;
                ymax[mrow] = vM; ymin[mrow] = vm;
            }
        }
        float ts = ssum + __shfl_xor(ssum, 1);
        float tq = ssq  + __shfl_xor(ssq, 1);
        if (kh == 0) {
            atomicAdd(stats + o, ts);
            atomicAdd(stats + CO + o, tq);
        }
        #undef LOADC
        #undef WRITEC
    }
}

// ---------------- epilogue: BN finalize (inlined) + relu(s*ext + b) ----------------
__global__ void k_out(const float* __restrict__ ymax, const float* __restrict__ ymin,
                      const float* __restrict__ stats, const float* __restrict__ gamma,
                      const float* __restrict__ beta, float* __restrict__ out_feat) {
    int tid = blockIdx.x * 256 + threadIdx.x;
    int o = tid & (CO - 1);
    const float inv = 1.f / (float)(MTOT * KNN);
    float mean = stats[o] * inv;
    float var = stats[CO + o] * inv - mean * mean;
    var = fmaxf(var, 0.f);
    float s = gamma[o] * rsqrtf(var + 1e-5f);
    float bb = beta[o] - mean * s;
    float yv = (s >= 0.f) ? ymax[tid] : ymin[tid];
    out_feat[tid] = fmaxf(fmaf(s, yv, bb), 0.f);
}

extern "C" void kernel_launch(void* const* d_in, const int* in_sizes, int n_in,
                              void* d_out, int out_size, void* d_ws, size_t ws_size,
                              hipStream_t stream) {
    const float* pts   = (const float*)d_in[0];
    const float* feat  = (const float*)d_in[1];
    const float* W     = (const float*)d_in[3];
    const float* gamma = (const float*)d_in[4];
    const float* beta  = (const float*)d_in[5];
    float* out = (float*)d_out;
    char* ws = (char*)d_ws;

    float4* qpts = (float4*)(ws);                       // 131072 B
    float*  stats = (float*)(ws + 655360);              // 1024 B
    u32*    prog  = (u32*)(ws + 656384);                // 512 B (4 batches x 128B apart)
    float*  ymax  = (float*)(ws + 657408);              // 4 MB
    float*  ymin  = (float*)(ws + 657408 + 4194304);    // 4 MB

    float* out_np   = out;                    // (8192,3)
    float* out_feat = out + 24576;            // (8192,128)
    float* out_rs   = out + 24576 + 1048576;  // (5,)

    hipLaunchKernelGGL(k_init,  dim3(1), dim3(256), 0, stream, stats, out_rs, prog);
    hipLaunchKernelGGL(k_mega,  dim3(NB + NB * CPB), dim3(256), 0, stream,
                       pts, feat, W, out_np, qpts, prog, ymax, ymin, stats);
    hipLaunchKernelGGL(k_out,   dim3(MTOT * CO / 256), dim3(256), 0, stream,
                       ymax, ymin, stats, gamma, beta, out_feat);
}

// Round 13
// 2018.382 us; speedup vs baseline: 1.2174x; 1.2174x over previous
//
#include <hip/hip_runtime.h>

#define NB 4
#define NPER 8192
#define MPER 2048
#define KNN 16
#define CIN 64
#define CO 128
#define MTOT (NB*MPER)
#define CPB 56          // knn chunks per batch: 24x64q + 8x32q + 8x16q + 16x8q

typedef unsigned long long u64;
typedef unsigned int u32;

__device__ __forceinline__ float med3f(float a, float b, float c) {
    return __builtin_amdgcn_fmed3f(a, b, c);
}

// ---------------- init: zero stats + progress, write row_splits ----------------
__global__ void k_init(float* __restrict__ stats, float* __restrict__ rs,
                       u32* __restrict__ prog) {
    int t = threadIdx.x;
    if (t < 256) stats[t] = 0.f;
    if (t < 128) prog[t] = 0u;
    if (t < 5) rs[t] = (float)(t * MPER);
}

// DPP compare-select step on a packed u64 key (max).
#define DPPSTEP(key, CTRL, RM) do {                                                   \
    unsigned lo_ = (unsigned)(key), hi_ = (unsigned)((key) >> 32);                    \
    unsigned nlo = (unsigned)__builtin_amdgcn_update_dpp((int)lo_, (int)lo_, CTRL, RM, 0xf, false); \
    unsigned nhi = (unsigned)__builtin_amdgcn_update_dpp((int)hi_, (int)hi_, CTRL, RM, 0xf, false); \
    unsigned long long ok_ = ((unsigned long long)nhi << 32) | nlo;                   \
    if (ok_ > (key)) (key) = ok_;                                                     \
} while (0)

#define DPP6(key) do { \
    DPPSTEP(key, 0xB1,  0xF); \
    DPPSTEP(key, 0x4E,  0xF); \
    DPPSTEP(key, 0x141, 0xF); \
    DPPSTEP(key, 0x140, 0xF); \
    DPPSTEP(key, 0x142, 0xA); \
    DPPSTEP(key, 0x143, 0xC); \
} while (0)

// ---------------- megakernel: blocks 0-3 = FPS, blocks 4-227 = KNN+stats ----------------
struct FpsSM {
    float4 spt[NPER];          // 128 KiB point table
    u64 red[2][4];             // parity-double-buffered wave partials
};
struct KnnSM {
    float4 sp[2][2112];        // staged chunk, per-sub stride P+2 (bank-safe)
    float  ndl[256][16];
    u32    candl[256][16];     // d < tau candidates (globally <= 15)
    u32    eql[256][16];       // d == tau candidates
    int    ccnt[256], ecnt[256];
    u32    pcur[256];
    float  taub[64];
    u32    nidxL[64][16];      // merged neighbor ids (global point ids)
    float4 g4[2][16][18];      // gather staging for stats (double-buffered)
};
#define SMBYTES (sizeof(FpsSM) > sizeof(KnnSM) ? sizeof(FpsSM) : sizeof(KnnSM))

__launch_bounds__(256, 1)
__global__ void k_mega(const float* __restrict__ pts, const float* __restrict__ feat,
                       const float* __restrict__ W, float* __restrict__ out_np,
                       float4* __restrict__ qpts, u32* __restrict__ prog,
                       float* __restrict__ ymax, float* __restrict__ ymin,
                       float* __restrict__ stats) {
    #pragma clang fp contract(off)
    __shared__ __align__(16) char SMRAW[SMBYTES];
    const int t = threadIdx.x;

    if (blockIdx.x < NB) {
        // ================= FPS (R2-proven body, 256 thr, 32 pts/lane) =================
        FpsSM& sm = *(FpsSM*)SMRAW;
        const int b = blockIdx.x;
        const float4* pb4 = (const float4*)(pts + (size_t)b * NPER * 3);

        float f[96];
        #pragma unroll
        for (int j = 0; j < 24; ++j) {
            float4 v = pb4[t * 24 + j];
            f[j*4+0] = v.x; f[j*4+1] = v.y; f[j*4+2] = v.z; f[j*4+3] = v.w;
        }
        float px[32], py[32], pz[32], dd[32];
        #pragma unroll
        for (int s = 0; s < 32; ++s) {
            px[s] = f[3*s]; py[s] = f[3*s+1]; pz[s] = f[3*s+2];
            dd[s] = 1e10f;
            sm.spt[t * 32 + s] = make_float4(px[s], py[s], pz[s], 0.f);
        }
        if (t == 0) {
            size_t row = (size_t)b * MPER;
            out_np[row*3+0] = px[0]; out_np[row*3+1] = py[0]; out_np[row*3+2] = pz[0];
            qpts[row] = make_float4(px[0], py[0], pz[0], 0.f);
        }
        __syncthreads();

        float4 c0 = sm.spt[0];
        float cx = c0.x, cy = c0.y, cz = c0.z;
        const int lane = t & 63, wv = t >> 6;
        const int ibase = t * 32;

        for (int i = 1; i < MPER; ++i) {
            float bv = -1.f; int bs = 0;
            #pragma unroll
            for (int s = 0; s < 32; ++s) {
                float dx = px[s] - cx, dy = py[s] - cy, dz = pz[s] - cz;
                float t0 = dx * dx, t1 = dy * dy, t2 = dz * dz;
                float d = (t0 + t1) + t2;
                float nd = fminf(dd[s], d);
                dd[s] = nd;
                bool bet = nd > bv;
                bv = bet ? nd : bv;
                bs = bet ? s : bs;
            }
            u64 key = ((u64)__float_as_uint(bv) << 32) | (u32)~(u32)(ibase + bs);

            DPP6(key);

            if (lane == 63) sm.red[i & 1][wv] = key;
            __syncthreads();

            // publisher on wave 1: all waves' global stores (rows <= i-1) were drained
            // by the barrier's vmcnt(0); release store does the L2 writeback.
            if (t == 64 && (((i & 127) == 0) || (i >= 1536 && (i & 31) == 0))) {
                __hip_atomic_store(prog + b * 32, (u32)i,
                                   __ATOMIC_RELEASE, __HIP_MEMORY_SCOPE_AGENT);
            }

            const int p = i & 1;
            u64 k0 = sm.red[p][0], k1 = sm.red[p][1], k2 = sm.red[p][2], k3 = sm.red[p][3];
            u64 ka = k0 > k1 ? k0 : k1;
            u64 kb = k2 > k3 ? k2 : k3;
            u64 kbest = ka > kb ? ka : kb;
            const int i2 = (int)(~(u32)kbest) & 0x1FFF;

            float4 c = sm.spt[i2];
            cx = c.x; cy = c.y; cz = c.z;

            if (t == 0) {
                size_t row = (size_t)b * MPER + i;
                out_np[row*3+0] = cx; out_np[row*3+1] = cy; out_np[row*3+2] = cz;
                qpts[row] = make_float4(cx, cy, cz, 0.f);
            }
        }
        __syncthreads();   // drains the final row's stores (vmcnt(0) per wave)
        if (t == 64) {
            __hip_atomic_store(prog + b * 32, (u32)MPER,
                               __ATOMIC_RELEASE, __HIP_MEMORY_SCOPE_AGENT);
        }
    } else {
        // ============ KNN (R9-proven math) + folded stats, gated on progress ============
        KnnSM& sm = *(KnnSM*)SMRAW;
        const int kb = blockIdx.x - NB;
        const int b  = kb / CPB;
        const int r  = kb % CPB;
        int nq, q0b;
        if (r < 24)      { nq = 64; q0b = r << 6; }
        else if (r < 32) { nq = 32; q0b = 1536 + ((r - 24) << 5); }
        else if (r < 40) { nq = 16; q0b = 1792 + ((r - 32) << 4); }
        else             { nq = 8;  q0b = 1920 + ((r - 40) << 3); }
        const int lgL = (nq == 64) ? 2 : (nq == 32) ? 3 : (nq == 16) ? 4 : 5;
        const int L = 1 << lgL;          // lanes per query
        const int lgP = 11 - lgL;
        const int P = 1 << lgP;          // points per lane per 2048-chunk
        const int stride = P + 2;        // float4 units; bank-offset 8 between subs
        const u32 need = (u32)(q0b + nq);

        // single-thread spin (de-stormed gate), then block-wide fence
        if (t == 0) {
            while (__hip_atomic_load(prog + b * 32, __ATOMIC_RELAXED,
                                     __HIP_MEMORY_SCOPE_AGENT) < need)
                __builtin_amdgcn_s_sleep(32);
        }
        __syncthreads();
        __threadfence();

        const int sub = t & (L - 1), qloc = t >> lgL;
        const int q = b * MPER + q0b + qloc;
        const float4 qp = qpts[q];
        const float qq = (qp.x * qp.x + qp.y * qp.y) + qp.z * qp.z;
        const float* pb = pts + (size_t)b * NPER * 3;
        const int wq = t >> 6, wl = t & 63;

        float4 Lr[6];
        #define LOADC(c) do { const float4* src_ = (const float4*)(pb + (size_t)(c) * 2048 * 3); \
            _Pragma("unroll") for (int u_ = 0; u_ < 6; ++u_) Lr[u_] = src_[t * 6 + u_]; } while (0)
        #define WRITEC(pbuf) do { \
            float fl_[24]; \
            _Pragma("unroll") for (int u_ = 0; u_ < 6; ++u_) { \
                fl_[u_*4+0]=Lr[u_].x; fl_[u_*4+1]=Lr[u_].y; fl_[u_*4+2]=Lr[u_].z; fl_[u_*4+3]=Lr[u_].w; } \
            _Pragma("unroll") for (int r_ = 0; r_ < 8; ++r_) { \
                float x_=fl_[3*r_], y_=fl_[3*r_+1], z_=fl_[3*r_+2]; \
                float pp_=(x_*x_ + y_*y_) + z_*z_; \
                int gpos_ = wq*512 + wl*8 + r_; \
                sm.sp[pbuf][(gpos_ >> lgP)*stride + (gpos_ & (P-1))] = make_float4(x_,y_,z_,pp_); } } while (0)

        // ---- pass 1: per-lane sorted top-16 distances over my P-pt sub-streams ----
        float nd[16];
        #pragma unroll
        for (int j = 0; j < 16; ++j) nd[j] = 1e30f;

        LOADC(0); WRITEC(0); LOADC(1);
        __syncthreads();
        for (int c = 0; c < 4; ++c) {
            const int pbuf = c & 1;
            const float4* rowp = &sm.sp[pbuf][sub * stride];
            #pragma unroll 4
            for (int j = 0; j < P; ++j) {
                float4 p = rowp[j];
                float dot = (qp.x * p.x + qp.y * p.y) + qp.z * p.z;
                float d = (qq + p.w) - 2.f * dot;
                if (d < nd[15]) {
                    #pragma unroll
                    for (int u = 15; u >= 1; --u) nd[u] = med3f(d, nd[u-1], nd[u]);
                    nd[0] = fminf(nd[0], d);
                }
            }
            __syncthreads();
            if (c < 3) {
                WRITEC((c + 1) & 1);
                if (c < 2) LOADC(c + 2);
                __syncthreads();
            }
        }
        #pragma unroll
        for (int j = 0; j < 16; ++j) sm.ndl[t][j] = nd[j];
        __syncthreads();

        // leader: exact 16th-smallest via med3-insertion over L sorted lists (early break)
        if (sub == 0) {
            float td[16];
            #pragma unroll
            for (int u = 0; u < 16; ++u) td[u] = 1e30f;
            for (int s = 0; s < L; ++s) {
                for (int u2 = 0; u2 < 16; ++u2) {
                    float v = sm.ndl[t + s][u2];
                    if (!(v < td[15])) break;     // row ascending -> rest can't insert
                    #pragma unroll
                    for (int u = 15; u >= 1; --u) td[u] = med3f(v, td[u-1], td[u]);
                    td[0] = fminf(td[0], v);
                }
            }
            sm.taub[qloc] = td[15];
        }
        __syncthreads();
        const float tau = sm.taub[qloc];

        // ---- pass 2: collect (d<tau) and (d==tau) separately (bit-identical recompute) ----
        int cnt = 0, ecn = 0;
        LOADC(0); WRITEC(0); LOADC(1);
        __syncthreads();
        for (int c = 0; c < 4; ++c) {
            const int pbuf = c & 1;
            const float4* rowp = &sm.sp[pbuf][sub * stride];
            for (int j = 0; j < P; ++j) {
                float4 p = rowp[j];
                float dot = (qp.x * p.x + qp.y * p.y) + qp.z * p.z;
                float d = (qq + p.w) - 2.f * dot;
                if (d <= tau) {
                    u32 pidx = (u32)(c * 2048 + (sub << lgP) + j);
                    if (d < tau) { if (cnt < 16) sm.candl[t][cnt++] = pidx; }
                    else         { if (ecn < 16) sm.eql[t][ecn++] = pidx; }
                }
            }
            __syncthreads();
            if (c < 3) {
                WRITEC((c + 1) & 1);
                if (c < 2) LOADC(c + 2);
                __syncthreads();
            }
        }
        sm.ccnt[t] = cnt; sm.ecnt[t] = ecn; sm.pcur[t] = 0;
        __syncthreads();

        // leader: all <tau cands (order-free downstream), then ascending-index quota
        // fill from ==tau cands. Identical SET to reference top_k. Stash in LDS.
        if (sub == 0) {
            const int base = t;
            int kept = 0;
            for (int s = 0; s < L; ++s) {
                int n = sm.ccnt[base + s];
                for (int e = 0; e < n && kept < 16; ++e)
                    sm.nidxL[qloc][kept++] = (u32)(b * NPER) + sm.candl[base + s][e];
            }
            while (kept < 16) {
                u32 best = 0xFFFFFFFFu; int bs = -1;
                for (int s = 0; s < L; ++s) {
                    u32 ps = sm.pcur[base + s];
                    u32 v = (ps < (u32)sm.ecnt[base + s]) ? sm.eql[base + s][ps] : 0xFFFFFFFFu;
                    if (v < best) { best = v; bs = s; }
                }
                if (bs < 0) break;
                sm.pcur[base + bs]++;
                sm.nidxL[qloc][kept++] = (u32)(b * NPER) + best;
            }
        }
        __syncthreads();

        // ---- folded stats phase: thread = (channel o = t>>1, k-half kh = t&1) ----
        const int o = t >> 1, kh = t & 1;
        float w[68];
        {
            const float* wr = W + o * 67;
            #pragma unroll
            for (int c = 0; c < 64; ++c) w[c] = wr[3 + c];
            w[64] = wr[0]; w[65] = wr[1]; w[66] = wr[2]; w[67] = 0.f;
        }
        const int gn = t >> 4, gf = t & 15;   // gather: neighbor, float4-slot
        float ssum = 0.f, ssq = 0.f;

        float4 gfv, gxv = make_float4(0.f, 0.f, 0.f, 0.f);
        {
            int nid = (int)sm.nidxL[0][gn];
            gfv = ((const float4*)(feat + (size_t)nid * CIN))[gf];
            if (t < 16) {
                int nid2 = (int)sm.nidxL[0][t];
                float4 qp2 = qpts[(size_t)b * MPER + q0b];
                gxv = make_float4(pts[(size_t)nid2*3]   - qp2.x,
                                  pts[(size_t)nid2*3+1] - qp2.y,
                                  pts[(size_t)nid2*3+2] - qp2.z, 0.f);
            }
        }
        for (int mi = 0; mi < nq; ++mi) {
            const int buf = mi & 1;
            sm.g4[buf][gn][gf] = gfv;
            if (t < 16) sm.g4[buf][t][16] = gxv;
            if (mi + 1 < nq) {
                int nid = (int)sm.nidxL[mi+1][gn];
                gfv = ((const float4*)(feat + (size_t)nid * CIN))[gf];
                if (t < 16) {
                    int nid2 = (int)sm.nidxL[mi+1][t];
                    float4 qp2 = qpts[(size_t)b * MPER + q0b + mi + 1];
                    gxv = make_float4(pts[(size_t)nid2*3]   - qp2.x,
                                      pts[(size_t)nid2*3+1] - qp2.y,
                                      pts[(size_t)nid2*3+2] - qp2.z, 0.f);
                }
            }
            __syncthreads();
            float vmax = -1e30f, vmin = 1e30f;
            #pragma unroll 1
            for (int kk = 0; kk < 8; ++kk) {
                const int k = kh * 8 + kk;
                float y0 = 0.f, y1 = 0.f, y2 = 0.f, y3 = 0.f;
                #pragma unroll
                for (int c4 = 0; c4 < 17; ++c4) {
                    float4 gv = sm.g4[buf][k][c4];
                    y0 = fmaf(gv.x, w[c4*4+0], y0);
                    y1 = fmaf(gv.y, w[c4*4+1], y1);
                    y2 = fmaf(gv.z, w[c4*4+2], y2);
                    y3 = fmaf(gv.w, w[c4*4+3], y3);
                }
                float y = (y0 + y1) + (y2 + y3);
                vmax = fmaxf(vmax, y); vmin = fminf(vmin, y);
                ssum += y; ssq = fmaf(y, y, ssq);
            }
            float vM = fmaxf(vmax, __shfl_xor(vmax, 1));
            float vm = fminf(vmin, __shfl_xor(vmin, 1));
            if (kh == 0) {
                size_t mrow = (size_t)(b * MPER + q0b + mi) * CO + o;
                ymax[mrow] = vM; ymin[mrow] = vm;
            }
        }
        float ts = ssum + __shfl_xor(ssum, 1);
        float tq = ssq  + __shfl_xor(ssq, 1);
        if (kh == 0) {
            atomicAdd(stats + o, ts);
            atomicAdd(stats + CO + o, tq);
        }
        #undef LOADC
        #undef WRITEC
    }
}

// ---------------- epilogue: BN finalize (inlined) + relu(s*ext + b) ----------------
__global__ void k_out(const float* __restrict__ ymax, const float* __restrict__ ymin,
                      const float* __restrict__ stats, const float* __restrict__ gamma,
                      const float* __restrict__ beta, float* __restrict__ out_feat) {
    int tid = blockIdx.x * 256 + threadIdx.x;
    int o = tid & (CO - 1);
    const float inv = 1.f / (float)(MTOT * KNN);
    float mean = stats[o] * inv;
    float var = stats[CO + o] * inv - mean * mean;
    var = fmaxf(var, 0.f);
    float s = gamma[o] * rsqrtf(var + 1e-5f);
    float bb = beta[o] - mean * s;
    float yv = (s >= 0.f) ? ymax[tid] : ymin[tid];
    out_feat[tid] = fmaxf(fmaf(s, yv, bb), 0.f);
}

extern "C" void kernel_launch(void* const* d_in, const int* in_sizes, int n_in,
                              void* d_out, int out_size, void* d_ws, size_t ws_size,
                              hipStream_t stream) {
    const float* pts   = (const float*)d_in[0];
    const float* feat  = (const float*)d_in[1];
    const float* W     = (const float*)d_in[3];
    const float* gamma = (const float*)d_in[4];
    const float* beta  = (const float*)d_in[5];
    float* out = (float*)d_out;
    char* ws = (char*)d_ws;

    float4* qpts = (float4*)(ws);                       // 131072 B
    float*  stats = (float*)(ws + 655360);              // 1024 B
    u32*    prog  = (u32*)(ws + 656384);                // 512 B (4 batches x 128B apart)
    float*  ymax  = (float*)(ws + 657408);              // 4 MB
    float*  ymin  = (float*)(ws + 657408 + 4194304);    // 4 MB

    float* out_np   = out;                    // (8192,3)
    float* out_feat = out + 24576;            // (8192,128)
    float* out_rs   = out + 24576 + 1048576;  // (5,)

    hipLaunchKernelGGL(k_init,  dim3(1), dim3(256), 0, stream, stats, out_rs, prog);
    hipLaunchKernelGGL(k_mega,  dim3(NB + NB * CPB), dim3(256), 0, stream,
                       pts, feat, W, out_np, qpts, prog, ymax, ymin, stats);
    hipLaunchKernelGGL(k_out,   dim3(MTOT * CO / 256), dim3(256), 0, stream,
                       ymax, ymin, stats, gamma, beta, out_feat);
}